// Round 2
// baseline (215.677 us; speedup 1.0000x reference)
//
#include <hip/hip_runtime.h>

// Problem geometry (fixed by setup_inputs): batch=256, N=65536, x is (256, 2N), w is (16, N).
#define NCOLS 65536
#define BATCH 256
#define TOTAL4 (BATCH * NCOLS / 4)   // 4,194,304 float4 output groups

typedef float f32x4 __attribute__((ext_vector_type(4)));

// Kernel 1: per-column softmax over 16 gate logits, folded through the constant
// W16_TO_4 matrix. One thread per column; loads of w[j*N + n] are coalesced
// across threads for each j. Output stored planar: wc[k*N + n], k=0..3.
// ~5 MiB of traffic -> a few microseconds; not the bottleneck.
__global__ void gate_precompute(const float* __restrict__ w, float* __restrict__ wc) {
    int n = blockIdx.x * blockDim.x + threadIdx.x;
    float e[16];
    float m = -INFINITY;
#pragma unroll
    for (int j = 0; j < 16; ++j) {
        e[j] = w[j * NCOLS + n];
        m = fmaxf(m, e[j]);
    }
    float s = 0.f;
#pragma unroll
    for (int j = 0; j < 16; ++j) {
        e[j] = __expf(e[j] - m);
        s += e[j];
    }
    float inv = 1.0f / s;
    // Rows of W16_TO_4 hardcoded (see reference _w16_to_4, incl. W[3,1] double-write):
    float c0 = (e[8] + e[9] + e[10] + e[11] + e[12] + e[13] + e[14] + e[15]) * inv;
    float c1 = (e[2] + e[3] + e[6] + e[7] - e[8] - e[9] - e[12] - e[13]) * inv;
    float c2 = (e[4] + e[5] + e[6] + e[7] - e[8] - e[9] - e[10] - e[11]) * inv;
    float c3 = (e[1] - e[2] - e[4] - 2.f * e[6] - e[7] + e[8] + 2.f * e[9] + e[11] + e[13] - e[14]) * inv;
    wc[0 * NCOLS + n] = c0;
    wc[1 * NCOLS + n] = c1;
    wc[2 * NCOLS + n] = c2;
    wc[3 * NCOLS + n] = c3;
}

// Kernel 2: memory-bound apply, grid-stride. Per float4-group i:
//   b = i>>14 (row), n4 = i&16383 (float4-column group).
// Reads 2x float4 of interleaved A/B from x (nontemporal: streamed once),
// 4x float4 coefficients (cached: reused 256x across batch rows),
// writes 1x float4 (nontemporal: never re-read).
__global__ __launch_bounds__(256) void gate_apply(const f32x4* __restrict__ x4,
                                                  const f32x4* __restrict__ wc4,
                                                  f32x4* __restrict__ out4) {
    int stride = gridDim.x * blockDim.x;
    for (int i = blockIdx.x * blockDim.x + threadIdx.x; i < TOTAL4; i += stride) {
        int b  = i >> 14;          // row index (16384 float4-groups per row)
        int n4 = i & 16383;        // float4-group within row
        const f32x4* xp = x4 + ((size_t)b << 15) + ((size_t)n4 << 1);
        f32x4 x0 = __builtin_nontemporal_load(xp);      // A[n],B[n],A[n+1],B[n+1]
        f32x4 x1 = __builtin_nontemporal_load(xp + 1);  // A[n+2],B[n+2],A[n+3],B[n+3]
        f32x4 c0 = wc4[0 * 16384 + n4];
        f32x4 c1 = wc4[1 * 16384 + n4];
        f32x4 c2 = wc4[2 * 16384 + n4];
        f32x4 c3 = wc4[3 * 16384 + n4];
        f32x4 a = {x0.x, x0.z, x1.x, x1.z};
        f32x4 bv = {x0.y, x0.w, x1.y, x1.w};
        f32x4 o = c0 + c1 * a + c2 * bv + c3 * (a * bv);
        __builtin_nontemporal_store(o, out4 + i);
    }
}

extern "C" void kernel_launch(void* const* d_in, const int* in_sizes, int n_in,
                              void* d_out, int out_size, void* d_ws, size_t ws_size,
                              hipStream_t stream) {
    const float* x = (const float*)d_in[0];   // (256, 131072) fp32
    const float* w = (const float*)d_in[1];   // (16, 65536) fp32
    float* out = (float*)d_out;               // (256, 65536) fp32
    float* wc = (float*)d_ws;                 // 4 * 65536 fp32 = 1 MiB scratch

    gate_precompute<<<NCOLS / 256, 256, 0, stream>>>(w, wc);

    // 2048 blocks = 8 blocks/CU on 256 CUs; each thread handles 8 float4 groups.
    gate_apply<<<2048, 256, 0, stream>>>((const f32x4*)x, (const f32x4*)wc, (f32x4*)out);
}

// Round 3
// 207.069 us; speedup vs baseline: 1.0416x; 1.0416x over previous
//
#include <hip/hip_runtime.h>

// Geometry fixed by setup_inputs: batch=256, N=65536, x is (256, 2N) fp32, w is (16, N) fp32.
#define NCOLS 65536
#define BATCH 256
#define CPB 512   // columns per block
#define RPB 16    // rows per block
// grid = (NCOLS/CPB) * (BATCH/RPB) = 128 * 16 = 2048 blocks x 256 threads

typedef float f32x4 __attribute__((ext_vector_type(4)));

// Single fused kernel. Phase 1: each block computes softmax-folded coefficients
// for its 512-column tile (2 cols/thread, coalesced per-row-of-w loads) into LDS.
// Redundancy: each column's softmax is computed 16x (once per row-chunk) -- total
// exp cost ~1us chip-wide, hidden under the memory stream; w (4 MiB) stays L2/L3
// resident. Phase 2: coefficients hoisted to registers, then stream 16 rows with
// nontemporal loads/stores (x and out are touched exactly once).
__global__ __launch_bounds__(256) void gate_fused(const float* __restrict__ x,
                                                  const float* __restrict__ w,
                                                  float* __restrict__ out) {
    __shared__ float wcs[4][CPB];
    const int tid = threadIdx.x;
    const int col_tile = blockIdx.x & 127;   // 128 column tiles
    const int row_chunk = blockIdx.x >> 7;   // 16 row chunks
    const int c0 = col_tile * CPB;
    const int r0 = row_chunk * RPB;

    // ---- Phase 1: softmax + W16_TO_4 fold for this block's columns ----
#pragma unroll
    for (int p = 0; p < 2; ++p) {
        int c = c0 + p * 256 + tid;
        float e[16];
        float m = -INFINITY;
#pragma unroll
        for (int j = 0; j < 16; ++j) {
            e[j] = w[j * NCOLS + c];   // lanes read consecutive columns: coalesced
            m = fmaxf(m, e[j]);
        }
        float s = 0.f;
#pragma unroll
        for (int j = 0; j < 16; ++j) {
            e[j] = __expf(e[j] - m);
            s += e[j];
        }
        float inv = 1.0f / s;
        int lc = p * 256 + tid;
        // Rows of W16_TO_4 hardcoded (incl. the W[3,1] double-write in the reference):
        wcs[0][lc] = (e[8] + e[9] + e[10] + e[11] + e[12] + e[13] + e[14] + e[15]) * inv;
        wcs[1][lc] = (e[2] + e[3] + e[6] + e[7] - e[8] - e[9] - e[12] - e[13]) * inv;
        wcs[2][lc] = (e[4] + e[5] + e[6] + e[7] - e[8] - e[9] - e[10] - e[11]) * inv;
        wcs[3][lc] = (e[1] - e[2] - e[4] - 2.f * e[6] - e[7] + e[8] + 2.f * e[9] + e[11] + e[13] - e[14]) * inv;
    }
    __syncthreads();

    // ---- Hoist this thread's coefficient group to registers (constant over rows) ----
    const int g = tid & 127;      // float4-group within the column tile
    const int rhalf = tid >> 7;   // which row of each row-pair
    f32x4 c0v = *(const f32x4*)&wcs[0][g * 4];
    f32x4 c1v = *(const f32x4*)&wcs[1][g * 4];
    f32x4 c2v = *(const f32x4*)&wcs[2][g * 4];
    f32x4 c3v = *(const f32x4*)&wcs[3][g * 4];

    // ---- Phase 2: stream 16 rows (2 per iteration), fully unrolled for ILP ----
#pragma unroll
    for (int it = 0; it < 8; ++it) {
        int r = r0 + rhalf + it * 2;
        const f32x4* xp = (const f32x4*)(x + (size_t)r * (2 * NCOLS) + (size_t)(c0 * 2 + g * 8));
        f32x4 x0 = __builtin_nontemporal_load(xp);      // A[n],B[n],A[n+1],B[n+1]
        f32x4 x1 = __builtin_nontemporal_load(xp + 1);  // A[n+2],B[n+2],A[n+3],B[n+3]
        f32x4 a  = {x0.x, x0.z, x1.x, x1.z};
        f32x4 bv = {x0.y, x0.w, x1.y, x1.w};
        f32x4 o = c0v + c1v * a + c2v * bv + c3v * (a * bv);
        __builtin_nontemporal_store(o, (f32x4*)(out + (size_t)r * NCOLS + c0 + g * 4));
    }
}

extern "C" void kernel_launch(void* const* d_in, const int* in_sizes, int n_in,
                              void* d_out, int out_size, void* d_ws, size_t ws_size,
                              hipStream_t stream) {
    const float* x = (const float*)d_in[0];   // (256, 131072) fp32
    const float* w = (const float*)d_in[1];   // (16, 65536) fp32
    float* out = (float*)d_out;               // (256, 65536) fp32
    (void)d_ws; (void)ws_size;

    gate_fused<<<(NCOLS / CPB) * (BATCH / RPB), 256, 0, stream>>>(x, w, out);
}

// Round 5
// 202.157 us; speedup vs baseline: 1.0669x; 1.0243x over previous
//
#include <hip/hip_runtime.h>

// Geometry fixed by setup_inputs: batch=256, N=65536, x is (256, 2N) fp32, w is (16, N) fp32.
#define NCOLS 65536
#define BATCH 256
#define CPB 512   // columns per block (= 2 per thread)
#define RPB 16    // rows per block
// grid = (NCOLS/CPB) * (BATCH/RPB) = 128 * 16 = 2048 blocks x 256 threads

typedef float f32x2 __attribute__((ext_vector_type(2)));
typedef float f32x4 __attribute__((ext_vector_type(4)));

// Fused kernel. Phase 1: per-block softmax + W16_TO_4 fold for its 512 columns
// (w is 4 MiB, re-read 16x but L2/L3-resident). Phase 2: thread t owns columns
// {2t, 2t+1}; per row it does ONE contiguous float4 NT load (the A/B pair for
// both columns -- wave covers 1 KiB contiguous, zero gaps), 6 VALU ops, ONE
// contiguous float2 NT store. Every memory instruction is fully coalesced, so
// no half-line waste regardless of NT cache behavior.
__global__ __launch_bounds__(256) void gate_fused(const float* __restrict__ x,
                                                  const float* __restrict__ w,
                                                  float* __restrict__ out) {
    __shared__ float wcs[4][CPB];
    const int tid = threadIdx.x;
    const int col_tile = blockIdx.x & 127;   // 128 column tiles
    const int row_chunk = blockIdx.x >> 7;   // 16 row chunks
    const int c0 = col_tile * CPB;
    const int r0 = row_chunk * RPB;

    // ---- Phase 1: softmax + W16_TO_4 fold ----
#pragma unroll
    for (int p = 0; p < 2; ++p) {
        int c = c0 + p * 256 + tid;
        float e[16];
        float m = -INFINITY;
#pragma unroll
        for (int j = 0; j < 16; ++j) {
            e[j] = w[j * NCOLS + c];   // coalesced per j
            m = fmaxf(m, e[j]);
        }
        float s = 0.f;
#pragma unroll
        for (int j = 0; j < 16; ++j) {
            e[j] = __expf(e[j] - m);
            s += e[j];
        }
        float inv = 1.0f / s;
        int lc = p * 256 + tid;
        // Rows of W16_TO_4 hardcoded (incl. the W[3,1] double-write in the reference):
        wcs[0][lc] = (e[8] + e[9] + e[10] + e[11] + e[12] + e[13] + e[14] + e[15]) * inv;
        wcs[1][lc] = (e[2] + e[3] + e[6] + e[7] - e[8] - e[9] - e[12] - e[13]) * inv;
        wcs[2][lc] = (e[4] + e[5] + e[6] + e[7] - e[8] - e[9] - e[10] - e[11]) * inv;
        wcs[3][lc] = (e[1] - e[2] - e[4] - 2.f * e[6] - e[7] + e[8] + 2.f * e[9] + e[11] + e[13] - e[14]) * inv;
    }
    __syncthreads();

    // ---- Per-thread coefficients for columns 2t, 2t+1 (ds_read_b64, 2-way = free) ----
    f32x2 k0 = *(const f32x2*)&wcs[0][tid * 2];
    f32x2 k1 = *(const f32x2*)&wcs[1][tid * 2];
    f32x2 k2 = *(const f32x2*)&wcs[2][tid * 2];
    f32x2 k3 = *(const f32x2*)&wcs[3][tid * 2];

    // ---- Phase 2: stream 16 rows, fully unrolled (16 independent loads in flight) ----
    const float* xbase = x + (size_t)r0 * (2 * NCOLS) + 2 * c0;
    float* obase = out + (size_t)r0 * NCOLS + c0;
#pragma unroll
    for (int it = 0; it < RPB; ++it) {
        const f32x4* xp = (const f32x4*)(xbase + (size_t)it * (2 * NCOLS)) + tid;
        f32x4 xv = __builtin_nontemporal_load(xp);   // A[2t],B[2t],A[2t+1],B[2t+1]
        f32x2 o;
        o.x = k0.x + k1.x * xv.x + k2.x * xv.y + k3.x * (xv.x * xv.y);
        o.y = k0.y + k1.y * xv.z + k2.y * xv.w + k3.y * (xv.z * xv.w);
        __builtin_nontemporal_store(o, (f32x2*)(obase + (size_t)it * NCOLS) + tid);
    }
}

extern "C" void kernel_launch(void* const* d_in, const int* in_sizes, int n_in,
                              void* d_out, int out_size, void* d_ws, size_t ws_size,
                              hipStream_t stream) {
    const float* x = (const float*)d_in[0];   // (256, 131072) fp32
    const float* w = (const float*)d_in[1];   // (16, 65536) fp32
    float* out = (float*)d_out;               // (256, 65536) fp32
    (void)d_ws; (void)ws_size;

    gate_fused<<<(NCOLS / CPB) * (BATCH / RPB), 256, 0, stream>>>(x, w, out);
}